// Round 9
// baseline (258.526 us; speedup 1.0000x reference)
//
#include <hip/hip_runtime.h>
#include <hip/hip_bf16.h>

#define S_LEN 4096
#define DM    512
#define NH    8
#define DK    64

typedef __attribute__((ext_vector_type(8))) __bf16 bf16x8;
typedef __attribute__((ext_vector_type(4))) float  f32x4;
typedef unsigned short u16;
typedef unsigned int   u32;
typedef unsigned long long u64;

// Q-GEMM epilogue scale: 1/sqrt(64) * log2(e)  (softmax in log2 domain)
#define SQ_SCALE (0.125f * 1.44269504f)
// Fixed softmax shift (log2-domain). Shift-invariant; l-division restores scale.
#define FMAX 12.0f

__device__ __forceinline__ u16 f2bf(float f) {
  union { float f; u32 i; } v; v.f = f;
  u32 r = v.i + 0x7fff + ((v.i >> 16) & 1);   // RNE
  return (u16)(r >> 16);
}
__device__ __forceinline__ float bf2f(u16 u) {
  union { u32 i; float f; } v; v.i = ((u32)u) << 16; return v.f;
}

// ---------------------------------------------------------------------------
// Pack mask [4096,4096] int32 (0/1) -> u64[4096][64]; bit=1 means masked.
__global__ __launch_bounds__(256) void pack_mask(const int* __restrict__ mask,
                                                 u64* __restrict__ out) {
  int gid = blockIdx.x * 256 + threadIdx.x;
  u64 b = __ballot(mask[gid] != 0);
  if ((threadIdx.x & 63) == 0) out[gid >> 6] = b;
}

// ---------------------------------------------------------------------------
// fp32 -> bf16 conversion; wq/wk/wv land contiguously (one [1536][512] matrix).
__global__ __launch_bounds__(256) void convert_all(
    const float* __restrict__ x, const float* __restrict__ wq,
    const float* __restrict__ wk, const float* __restrict__ wv,
    const float* __restrict__ dw,
    u16* __restrict__ xb, u16* __restrict__ wcat, u16* __restrict__ dwb) {
  int b = blockIdx.x;
  const float* src; u16* dst; size_t off;
  if      (b < 2048) { src = x;  dst = xb;   off = (size_t)b * 1024; }
  else if (b < 2304) { src = wq; dst = wcat; off = (size_t)(b - 2048) * 1024; }
  else if (b < 2560) { src = wk; dst = wcat + 262144; off = (size_t)(b - 2304) * 1024; }
  else if (b < 2816) { src = wv; dst = wcat + 524288; off = (size_t)(b - 2560) * 1024; }
  else               { src = dw; dst = dwb;  off = (size_t)(b - 2816) * 1024; }
  size_t i = off + (size_t)threadIdx.x * 4;
  float4 v = *reinterpret_cast<const float4*>(src + i);
  ushort4 o = make_ushort4(f2bf(v.x), f2bf(v.y), f2bf(v.z), f2bf(v.w));
  *reinterpret_cast<ushort4*>(dst + i) = o;
}

// ---------------------------------------------------------------------------
// Fused QKV projection, 64x64 tiles: C[4096,1536] = x @ Wcat^T + bias.
// grid (24, 64). seg 0=Q (scaled), 1=K, 2=V.
// V output layout Vt2[(h*64+d)][c*512 + m'] where key s = m'*8 + c.
__global__ __launch_bounds__(256) void qkv_gemm(
    const u16* __restrict__ A, const u16* __restrict__ Wcat,
    const float* __restrict__ bq, const float* __restrict__ bk,
    const float* __restrict__ bv,
    u16* __restrict__ Qb, u16* __restrict__ Kb, u16* __restrict__ Vt2) {
  __shared__ u16 As[64 * 72];
  __shared__ u16 Ws[64 * 72];
  const int t = threadIdx.x;
  const int lane = t & 63, wv = t >> 6;
  const int m16 = lane & 15, quad = lane >> 4;
  const int n0g = blockIdx.x * 64, m0 = blockIdx.y * 64;
  const int seg = n0g >> 9;
  const int n0 = n0g & 511;

  f32x4 acc[4];
#pragma unroll
  for (int j = 0; j < 4; j++) acc[j] = (f32x4)0.f;

  for (int k0 = 0; k0 < DM; k0 += 64) {
    __syncthreads();
#pragma unroll
    for (int c0 = 0; c0 < 2; c0++) {
      int c = t + c0 * 256;
      int row = c >> 3, col = (c & 7) * 8;
      *reinterpret_cast<uint4*>(&As[row * 72 + col]) =
          *reinterpret_cast<const uint4*>(&A[(size_t)(m0 + row) * DM + k0 + col]);
      *reinterpret_cast<uint4*>(&Ws[row * 72 + col]) =
          *reinterpret_cast<const uint4*>(&Wcat[(size_t)(n0g + row) * DM + k0 + col]);
    }
    __syncthreads();
#pragma unroll
    for (int kk = 0; kk < 64; kk += 32) {
      bf16x8 a = *reinterpret_cast<const bf16x8*>(&As[(wv * 16 + m16) * 72 + quad * 8 + kk]);
#pragma unroll
      for (int ct = 0; ct < 4; ct++) {
        bf16x8 b = *reinterpret_cast<const bf16x8*>(&Ws[(ct * 16 + m16) * 72 + quad * 8 + kk]);
        acc[ct] = __builtin_amdgcn_mfma_f32_16x16x32_bf16(a, b, acc[ct], 0, 0, 0);
      }
    }
  }

  const float* bias = (seg == 0) ? bq : (seg == 1) ? bk : bv;
  const float scale = (seg == 0) ? SQ_SCALE : 1.f;
  float bn[4];
#pragma unroll
  for (int ct = 0; ct < 4; ct++) bn[ct] = bias[n0 + ct * 16 + m16];

  if (seg == 2) {
    // transpose tile through LDS: T[d][m-local], then contiguous uint4 stores
    __syncthreads();   // done reading As/Ws
    u16* T = As;
#pragma unroll
    for (int ct = 0; ct < 4; ct++)
#pragma unroll
      for (int r = 0; r < 4; r++)
        T[(ct * 16 + m16) * 72 + wv * 16 + quad * 4 + r] = f2bf(acc[ct][r] + bn[ct]);
    __syncthreads();
    const int h = m0 >> 9;
    const int cseg = n0 >> 6;
    const int mp = m0 & 511;
#pragma unroll
    for (int c0 = 0; c0 < 2; c0++) {
      int c = t + c0 * 256;
      int d = c >> 3, col8 = (c & 7) * 8;
      *reinterpret_cast<uint4*>(
          &Vt2[(size_t)(h * 64 + d) * S_LEN + cseg * 512 + mp + col8]) =
          *reinterpret_cast<const uint4*>(&T[d * 72 + col8]);
    }
  } else {
    u16* dst = (seg == 0) ? Qb : Kb;
#pragma unroll
    for (int ct = 0; ct < 4; ct++) {
      int n = n0 + ct * 16 + m16;
#pragma unroll
      for (int r = 0; r < 4; r++) {
        int m = m0 + wv * 16 + quad * 4 + r;
        dst[(size_t)m * DM + n] = f2bf((acc[ct][r] + bn[ct]) * scale);
      }
    }
  }
}

// ---------------------------------------------------------------------------
// Dense out-proj, 64x64 tiles: C[4096,512](f32) = A @ dw^T + db. grid (8,64).
__global__ __launch_bounds__(256) void dense_gemm(
    const u16* __restrict__ A, const u16* __restrict__ W,
    const float* __restrict__ bias, float* __restrict__ Cout) {
  __shared__ u16 As[64 * 72];
  __shared__ u16 Ws[64 * 72];
  const int t = threadIdx.x;
  const int lane = t & 63, wv = t >> 6;
  const int m16 = lane & 15, quad = lane >> 4;
  const int n0 = blockIdx.x * 64, m0 = blockIdx.y * 64;

  f32x4 acc[4];
#pragma unroll
  for (int j = 0; j < 4; j++) acc[j] = (f32x4)0.f;

  for (int k0 = 0; k0 < DM; k0 += 64) {
    __syncthreads();
#pragma unroll
    for (int c0 = 0; c0 < 2; c0++) {
      int c = t + c0 * 256;
      int row = c >> 3, col = (c & 7) * 8;
      *reinterpret_cast<uint4*>(&As[row * 72 + col]) =
          *reinterpret_cast<const uint4*>(&A[(size_t)(m0 + row) * DM + k0 + col]);
      *reinterpret_cast<uint4*>(&Ws[row * 72 + col]) =
          *reinterpret_cast<const uint4*>(&W[(size_t)(n0 + row) * DM + k0 + col]);
    }
    __syncthreads();
#pragma unroll
    for (int kk = 0; kk < 64; kk += 32) {
      bf16x8 a = *reinterpret_cast<const bf16x8*>(&As[(wv * 16 + m16) * 72 + quad * 8 + kk]);
#pragma unroll
      for (int ct = 0; ct < 4; ct++) {
        bf16x8 b = *reinterpret_cast<const bf16x8*>(&Ws[(ct * 16 + m16) * 72 + quad * 8 + kk]);
        acc[ct] = __builtin_amdgcn_mfma_f32_16x16x32_bf16(a, b, acc[ct], 0, 0, 0);
      }
    }
  }

  float bn[4];
#pragma unroll
  for (int ct = 0; ct < 4; ct++) bn[ct] = bias[n0 + ct * 16 + m16];
#pragma unroll
  for (int ct = 0; ct < 4; ct++) {
    int n = n0 + ct * 16 + m16;
#pragma unroll
    for (int r = 0; r < 4; r++) {
      int m = m0 + wv * 16 + quad * 4 + r;
      Cout[(size_t)m * DM + n] = acc[ct][r] + bn[ct];
    }
  }
}

// ---------------------------------------------------------------------------
// Flash attention, MFMA, fixed-shift softmax, GRID split-K x2 (blockIdx.z).
// Block = 256 thr (4 waves x 16 q-rows), q-tile 64, one key half of 2048.
// Partial O (bf16, unnormalized) + partial l (f32) out; merged by attn_merge.
// K LDS uses per-row column rotation (colblk + row>>3)&7 to kill the 8-way
// staging-write bank conflict of the ktil permutation (rperm stride 8).
__global__ __launch_bounds__(256, 5) void attn_mfma(
    const u16* __restrict__ Q, const u16* __restrict__ K,
    const u16* __restrict__ Vt2, const u64* __restrict__ mbits,
    u16* __restrict__ Op, float* __restrict__ Lp) {
  __shared__ u16 Ks[64 * 72];
  __shared__ u16 Vs[64 * 72];
  __shared__ u16 Ps[64 * 72];

  const int t = threadIdx.x;
  const int lane = t & 63, w4 = t >> 6;
  const int m16 = lane & 15, quad = lane >> 4;
  const int q0 = blockIdx.x * 64;
  const int h = blockIdx.y;
  const int g = blockIdx.z;          // key half
  const size_t hoff = (size_t)h * S_LEN * DK;
  const size_t kbase = hoff + (size_t)g * 2048 * DK;
  const u16* V2h = Vt2 + (size_t)h * DK * S_LEN;

  // Q fragments straight from global (pre-scaled by 0.125*log2e in Q-GEMM)
  const u16* qptr = Q + hoff + (size_t)(q0 + w4 * 16 + m16) * DK + quad * 8;
  bf16x8 qlo = *reinterpret_cast<const bf16x8*>(qptr);
  bf16x8 qhi = *reinterpret_cast<const bf16x8*>(qptr + 32);

  // ones B-fragment (row-sum of P via MFMA)
  union { u16 u[8]; bf16x8 v; } onesu;
#pragma unroll
  for (int j = 0; j < 8; j++) onesu.u[j] = 0x3F80;
  const bf16x8 ones = onesu.v;

  f32x4 acc_o[4];
  f32x4 acc_l = (f32x4)0.f;
#pragma unroll
  for (int dt = 0; dt < 4; dt++) acc_o[dt] = (f32x4)0.f;

  const int mshift = 32 * (quad & 1) + (quad >> 1);
  const int prow = (w4 * 16 + m16) * 72;

  for (int k0 = 0; k0 < 2048; k0 += 64) {
    const int kg = g * 2048 + k0;   // global key tile base
    // stage K permuted+rotated; stage V from Vt2 (contiguous, lands permuted)
#pragma unroll
    for (int c0 = 0; c0 < 2; c0++) {
      int c = t + c0 * 256;
      int rg = c >> 3, cc = c & 7;
      int rperm = ((rg & 7) << 3) | (rg >> 3);
      int ccp = (cc + (rg & 7)) & 7;          // rotation by rperm>>3 = rg&7
      *reinterpret_cast<uint4*>(&Ks[rperm * 72 + ccp * 8]) =
          *reinterpret_cast<const uint4*>(&K[kbase + (size_t)(k0 + rg) * DK + cc * 8]);
      *reinterpret_cast<uint4*>(&Vs[rg * 72 + cc * 8]) =
          *reinterpret_cast<const uint4*>(&V2h[(size_t)rg * S_LEN + cc * 512 + (kg >> 3)]);
    }
    // one mask word per lane: query q0+w4*16+m16, keys [kg, kg+64)
    u64 mq = mbits[(size_t)(q0 + w4 * 16 + m16) * 64 + (kg >> 6)];
    u32 mm = (u32)(mq >> mshift);
    __syncthreads();   // tiles ready

    // S^T - FMAX = K @ Q^T (acc pre-initialized to -FMAX)
    f32x4 s[4];
#pragma unroll
    for (int ct = 0; ct < 4; ct++) s[ct] = (f32x4)(-FMAX);
#pragma unroll
    for (int ct = 0; ct < 4; ct++) {
      int R = ct * 16 + m16;
      int pclo = (quad + 2 * ct + (m16 >> 3)) & 7;   // rotated colblk
      bf16x8 klo = *reinterpret_cast<const bf16x8*>(&Ks[R * 72 + pclo * 8]);
      bf16x8 khi = *reinterpret_cast<const bf16x8*>(&Ks[R * 72 + (pclo ^ 4) * 8]);
      s[ct] = __builtin_amdgcn_mfma_f32_16x16x32_bf16(klo, qlo, s[ct], 0, 0, 0);
      s[ct] = __builtin_amdgcn_mfma_f32_16x16x32_bf16(khi, qhi, s[ct], 0, 0, 0);
    }

    // p = exp2(s), masked -> 0; pack pairs via biased-round + v_perm
#pragma unroll
    for (int ct = 0; ct < 4; ct++) {
      float p0 = __builtin_amdgcn_exp2f(((mm >> (2 * ct)) & 1u)      ? -1e9f : s[ct][0]);
      float p1 = __builtin_amdgcn_exp2f(((mm >> (8 + 2 * ct)) & 1u)  ? -1e9f : s[ct][1]);
      float p2 = __builtin_amdgcn_exp2f(((mm >> (16 + 2 * ct)) & 1u) ? -1e9f : s[ct][2]);
      float p3 = __builtin_amdgcn_exp2f(((mm >> (24 + 2 * ct)) & 1u) ? -1e9f : s[ct][3]);
      u32 pk01 = __builtin_amdgcn_perm(__float_as_uint(p1) + 0x8000u,
                                       __float_as_uint(p0) + 0x8000u, 0x07060302u);
      u32 pk23 = __builtin_amdgcn_perm(__float_as_uint(p3) + 0x8000u,
                                       __float_as_uint(p2) + 0x8000u, 0x07060302u);
      *reinterpret_cast<uint2*>(&Ps[prow + ct * 16 + quad * 4]) = make_uint2(pk01, pk23);
    }
    // Ps rows are wave-private: no barrier needed.

    // O += P @ V ; l += P @ 1   (all in permuted key space)
    bf16x8 plo = *reinterpret_cast<const bf16x8*>(&Ps[prow + quad * 8]);
    bf16x8 phi = *reinterpret_cast<const bf16x8*>(&Ps[prow + quad * 8 + 32]);
#pragma unroll
    for (int dt = 0; dt < 4; dt++) {
      bf16x8 vlo = *reinterpret_cast<const bf16x8*>(&Vs[(dt * 16 + m16) * 72 + quad * 8]);
      bf16x8 vhi = *reinterpret_cast<const bf16x8*>(&Vs[(dt * 16 + m16) * 72 + quad * 8 + 32]);
      acc_o[dt] = __builtin_amdgcn_mfma_f32_16x16x32_bf16(plo, vlo, acc_o[dt], 0, 0, 0);
      acc_o[dt] = __builtin_amdgcn_mfma_f32_16x16x32_bf16(phi, vhi, acc_o[dt], 0, 0, 0);
    }
    acc_l = __builtin_amdgcn_mfma_f32_16x16x32_bf16(plo, ones, acc_l, 0, 0, 0);
    acc_l = __builtin_amdgcn_mfma_f32_16x16x32_bf16(phi, ones, acc_l, 0, 0, 0);
    __syncthreads();   // all reads done before next staging
  }

  // write partial O (unnormalized bf16) + partial l (f32)
  u16* Og = Op + (size_t)g * 2097152;
#pragma unroll
  for (int dt = 0; dt < 4; dt++)
#pragma unroll
    for (int r = 0; r < 4; r++)
      Og[(size_t)(q0 + w4 * 16 + quad * 4 + r) * DM + h * DK + dt * 16 + m16] =
          f2bf(acc_o[dt][r]);
  if (m16 == 0) {
#pragma unroll
    for (int r = 0; r < 4; r++)
      Lp[g * 32768 + h * 4096 + q0 + w4 * 16 + quad * 4 + r] = acc_l[r];
  }
}

// ---------------------------------------------------------------------------
// Merge the two key-half partials: Out = (O0 + O1) / (l0 + l1). bf16 out.
__global__ __launch_bounds__(256) void attn_merge(
    const u16* __restrict__ Op, const float* __restrict__ Lp,
    u16* __restrict__ Out) {
  int i8 = (blockIdx.x * 256 + threadIdx.x) * 8;   // 8 elems/thread, same (q,h)
  int q = i8 >> 9;
  int h = (i8 >> 6) & 7;
  float rl = 1.f / (Lp[h * 4096 + q] + Lp[32768 + h * 4096 + q]);
  ushort4 a0 = *reinterpret_cast<const ushort4*>(Op + i8);
  ushort4 a1 = *reinterpret_cast<const ushort4*>(Op + i8 + 4);
  ushort4 b0 = *reinterpret_cast<const ushort4*>(Op + 2097152 + i8);
  ushort4 b1 = *reinterpret_cast<const ushort4*>(Op + 2097152 + i8 + 4);
  ushort4 o0 = make_ushort4(f2bf((bf2f(a0.x) + bf2f(b0.x)) * rl),
                            f2bf((bf2f(a0.y) + bf2f(b0.y)) * rl),
                            f2bf((bf2f(a0.z) + bf2f(b0.z)) * rl),
                            f2bf((bf2f(a0.w) + bf2f(b0.w)) * rl));
  ushort4 o1 = make_ushort4(f2bf((bf2f(a1.x) + bf2f(b1.x)) * rl),
                            f2bf((bf2f(a1.y) + bf2f(b1.y)) * rl),
                            f2bf((bf2f(a1.z) + bf2f(b1.z)) * rl),
                            f2bf((bf2f(a1.w) + bf2f(b1.w)) * rl));
  *reinterpret_cast<ushort4*>(Out + i8) = o0;
  *reinterpret_cast<ushort4*>(Out + i8 + 4) = o1;
}

// ---------------------------------------------------------------------------
extern "C" void kernel_launch(void* const* d_in, const int* in_sizes, int n_in,
                              void* d_out, int out_size, void* d_ws, size_t ws_size,
                              hipStream_t stream) {
  const float* x    = (const float*)d_in[0];
  const int*   mask = (const int*)d_in[1];
  const float* wq_w = (const float*)d_in[2];
  const float* wq_b = (const float*)d_in[3];
  const float* wk_w = (const float*)d_in[4];
  const float* wk_b = (const float*)d_in[5];
  const float* wv_w = (const float*)d_in[6];
  const float* wv_b = (const float*)d_in[7];
  const float* dw   = (const float*)d_in[8];
  const float* db   = (const float*)d_in[9];

  // ws (u16 elems): xb 2M | wcat 768K | dwb 256K | Qb/Kb/Vt2 2M each |
  // Opart 4M (two bf16 partials) | mb 256K u64 | Lp 64K f32.  ~28.3 MB.
  u16* xb    = (u16*)d_ws;
  u16* wcat  = xb    + 2097152;
  u16* dwb   = wcat  + 786432;
  u16* Qb    = dwb   + 262144;
  u16* Kb    = Qb    + 2097152;
  u16* Vt2   = Kb    + 2097152;
  u16* Opart = Vt2   + 2097152;
  u64* mb    = (u64*)(Opart + 4194304);
  float* Lp  = (float*)(mb + 262144);

  pack_mask<<<(S_LEN * S_LEN) / 256, 256, 0, stream>>>(mask, mb);
  convert_all<<<3072, 256, 0, stream>>>(x, wq_w, wk_w, wv_w, dw, xb, wcat, dwb);

  qkv_gemm<<<dim3(24, 64), 256, 0, stream>>>(xb, wcat, wq_b, wk_b, wv_b,
                                             Qb, Kb, Vt2);

  attn_mfma<<<dim3(S_LEN / 64, NH, 2), 256, 0, stream>>>(Qb, Kb, Vt2, mb,
                                                         Opart, Lp);
  attn_merge<<<1024, 256, 0, stream>>>(Opart, Lp, Qb);

  dense_gemm<<<dim3(8, 64), 256, 0, stream>>>(Qb, dwb, db, (float*)d_out);
}

// Round 11
// 239.685 us; speedup vs baseline: 1.0786x; 1.0786x over previous
//
#include <hip/hip_runtime.h>
#include <hip/hip_bf16.h>

#define S_LEN 4096
#define DM    512
#define NH    8
#define DK    64

typedef __attribute__((ext_vector_type(8))) __bf16 bf16x8;
typedef __attribute__((ext_vector_type(4))) float  f32x4;
typedef unsigned short u16;
typedef unsigned int   u32;
typedef unsigned long long u64;

// Q-GEMM epilogue scale: 1/sqrt(64) * log2(e)  (softmax in log2 domain)
#define SQ_SCALE (0.125f * 1.44269504f)
// Fixed softmax shift (log2-domain). Shift-invariant; l-division restores scale.
#define FMAX 12.0f

__device__ __forceinline__ u16 f2bf(float f) {
  union { float f; u32 i; } v; v.f = f;
  u32 r = v.i + 0x7fff + ((v.i >> 16) & 1);   // RNE
  return (u16)(r >> 16);
}

// ---------------------------------------------------------------------------
// Pack mask [4096,4096] int32 (0/1) -> u64[4096][64]; bit=1 means masked.
__global__ __launch_bounds__(256) void pack_mask(const int* __restrict__ mask,
                                                 u64* __restrict__ out) {
  int gid = blockIdx.x * 256 + threadIdx.x;
  u64 b = __ballot(mask[gid] != 0);
  if ((threadIdx.x & 63) == 0) out[gid >> 6] = b;
}

// ---------------------------------------------------------------------------
// fp32 -> bf16 conversion; wq/wk/wv land contiguously (one [1536][512] matrix).
__global__ __launch_bounds__(256) void convert_all(
    const float* __restrict__ x, const float* __restrict__ wq,
    const float* __restrict__ wk, const float* __restrict__ wv,
    const float* __restrict__ dw,
    u16* __restrict__ xb, u16* __restrict__ wcat, u16* __restrict__ dwb) {
  int b = blockIdx.x;
  const float* src; u16* dst; size_t off;
  if      (b < 2048) { src = x;  dst = xb;   off = (size_t)b * 1024; }
  else if (b < 2304) { src = wq; dst = wcat; off = (size_t)(b - 2048) * 1024; }
  else if (b < 2560) { src = wk; dst = wcat + 262144; off = (size_t)(b - 2304) * 1024; }
  else if (b < 2816) { src = wv; dst = wcat + 524288; off = (size_t)(b - 2560) * 1024; }
  else               { src = dw; dst = dwb;  off = (size_t)(b - 2816) * 1024; }
  size_t i = off + (size_t)threadIdx.x * 4;
  float4 v = *reinterpret_cast<const float4*>(src + i);
  ushort4 o = make_ushort4(f2bf(v.x), f2bf(v.y), f2bf(v.z), f2bf(v.w));
  *reinterpret_cast<ushort4*>(dst + i) = o;
}

// ---------------------------------------------------------------------------
// Fused QKV projection, 64(m) x 128(n) tiles: C[4096,1536] = x @ Wcat^T + bias.
// grid (12, 64), 256 thr, wave quadrant = 32(m) x 64(n), acc 2x4.
// 16 MFMAs + 12 ds_read_b128 per K-iter (2x density vs 64x64).
// seg 0=Q (scaled), 1=K, 2=V (Vt2[(h*64+d)][c*512+m'] via LDS transpose).
__global__ __launch_bounds__(256) void qkv_gemm(
    const u16* __restrict__ A, const u16* __restrict__ Wcat,
    const float* __restrict__ bq, const float* __restrict__ bk,
    const float* __restrict__ bv,
    u16* __restrict__ Qb, u16* __restrict__ Kb, u16* __restrict__ Vt2) {
  __shared__ u16 As[64 * 72];    // 9.2 KB
  __shared__ u16 Ws[128 * 72];   // 18.4 KB (reused as T in V epilogue)
  const int t = threadIdx.x;
  const int lane = t & 63, wv = t >> 6;
  const int m16 = lane & 15, quad = lane >> 4;
  const int n0g = blockIdx.x * 128, m0 = blockIdx.y * 64;
  const int seg = n0g >> 9;          // 0=Q 1=K 2=V (128-tile within one segment)
  const int n0 = n0g & 511;
  const int mq = wv >> 1, nq = wv & 1;   // wave quadrant

  f32x4 acc[2][4];
#pragma unroll
  for (int i = 0; i < 2; i++)
#pragma unroll
    for (int j = 0; j < 4; j++) acc[i][j] = (f32x4)0.f;

  for (int k0 = 0; k0 < DM; k0 += 64) {
    __syncthreads();
#pragma unroll
    for (int c0 = 0; c0 < 2; c0++) {       // A: 64x64 = 512 uint4
      int c = t + c0 * 256;
      int row = c >> 3, col = (c & 7) * 8;
      *reinterpret_cast<uint4*>(&As[row * 72 + col]) =
          *reinterpret_cast<const uint4*>(&A[(size_t)(m0 + row) * DM + k0 + col]);
    }
#pragma unroll
    for (int c0 = 0; c0 < 4; c0++) {       // W: 128x64 = 1024 uint4
      int c = t + c0 * 256;
      int row = c >> 3, col = (c & 7) * 8;
      *reinterpret_cast<uint4*>(&Ws[row * 72 + col]) =
          *reinterpret_cast<const uint4*>(&Wcat[(size_t)(n0g + row) * DM + k0 + col]);
    }
    __syncthreads();
#pragma unroll
    for (int kk = 0; kk < 64; kk += 32) {
      bf16x8 a0 = *reinterpret_cast<const bf16x8*>(&As[(mq * 32 + m16) * 72 + quad * 8 + kk]);
      bf16x8 a1 = *reinterpret_cast<const bf16x8*>(&As[(mq * 32 + 16 + m16) * 72 + quad * 8 + kk]);
#pragma unroll
      for (int ct = 0; ct < 4; ct++) {
        bf16x8 b = *reinterpret_cast<const bf16x8*>(&Ws[(nq * 64 + ct * 16 + m16) * 72 + quad * 8 + kk]);
        acc[0][ct] = __builtin_amdgcn_mfma_f32_16x16x32_bf16(a0, b, acc[0][ct], 0, 0, 0);
        acc[1][ct] = __builtin_amdgcn_mfma_f32_16x16x32_bf16(a1, b, acc[1][ct], 0, 0, 0);
      }
    }
  }

  const float* bias = (seg == 0) ? bq : (seg == 1) ? bk : bv;
  const float scale = (seg == 0) ? SQ_SCALE : 1.f;
  float bn[4];
#pragma unroll
  for (int ct = 0; ct < 4; ct++) bn[ct] = bias[n0 + nq * 64 + ct * 16 + m16];

  if (seg == 2) {
    // transpose through LDS (reuse Ws as T[128 n-local][64 m-local], stride 72)
    __syncthreads();   // all fragment reads of Ws done
    u16* T = Ws;
#pragma unroll
    for (int rt = 0; rt < 2; rt++)
#pragma unroll
      for (int ct = 0; ct < 4; ct++)
#pragma unroll
        for (int r = 0; r < 4; r++)
          T[(nq * 64 + ct * 16 + m16) * 72 + mq * 32 + rt * 16 + quad * 4 + r] =
              f2bf(acc[rt][ct][r] + bn[ct]);
    __syncthreads();
    const int h  = m0 >> 9;
    const int mp = m0 & 511;
#pragma unroll
    for (int c0 = 0; c0 < 4; c0++) {       // 128x64 = 1024 uint4 copies
      int c = t + c0 * 256;
      int nl = c >> 3, col8 = (c & 7) * 8;
      int d  = (n0 + nl) & 63;
      int cc = (n0 + nl) >> 6;
      *reinterpret_cast<uint4*>(
          &Vt2[(size_t)(h * 64 + d) * S_LEN + cc * 512 + mp + col8]) =
          *reinterpret_cast<const uint4*>(&T[nl * 72 + col8]);
    }
  } else {
    u16* dst = (seg == 0) ? Qb : Kb;
#pragma unroll
    for (int rt = 0; rt < 2; rt++)
#pragma unroll
      for (int ct = 0; ct < 4; ct++) {
        int n = n0 + nq * 64 + ct * 16 + m16;
#pragma unroll
        for (int r = 0; r < 4; r++) {
          int m = m0 + mq * 32 + rt * 16 + quad * 4 + r;
          dst[(size_t)m * DM + n] = f2bf((acc[rt][ct][r] + bn[ct]) * scale);
        }
      }
  }
}

// ---------------------------------------------------------------------------
// Dense out-proj, 64x64 tiles: C[4096,512](f32) = A @ dw^T + db. grid (8,64).
__global__ __launch_bounds__(256) void dense_gemm(
    const u16* __restrict__ A, const u16* __restrict__ W,
    const float* __restrict__ bias, float* __restrict__ Cout) {
  __shared__ u16 As[64 * 72];
  __shared__ u16 Ws[64 * 72];
  const int t = threadIdx.x;
  const int lane = t & 63, wv = t >> 6;
  const int m16 = lane & 15, quad = lane >> 4;
  const int n0 = blockIdx.x * 64, m0 = blockIdx.y * 64;

  f32x4 acc[4];
#pragma unroll
  for (int j = 0; j < 4; j++) acc[j] = (f32x4)0.f;

  for (int k0 = 0; k0 < DM; k0 += 64) {
    __syncthreads();
#pragma unroll
    for (int c0 = 0; c0 < 2; c0++) {
      int c = t + c0 * 256;
      int row = c >> 3, col = (c & 7) * 8;
      *reinterpret_cast<uint4*>(&As[row * 72 + col]) =
          *reinterpret_cast<const uint4*>(&A[(size_t)(m0 + row) * DM + k0 + col]);
      *reinterpret_cast<uint4*>(&Ws[row * 72 + col]) =
          *reinterpret_cast<const uint4*>(&W[(size_t)(n0 + row) * DM + k0 + col]);
    }
    __syncthreads();
#pragma unroll
    for (int kk = 0; kk < 64; kk += 32) {
      bf16x8 a = *reinterpret_cast<const bf16x8*>(&As[(wv * 16 + m16) * 72 + quad * 8 + kk]);
#pragma unroll
      for (int ct = 0; ct < 4; ct++) {
        bf16x8 b = *reinterpret_cast<const bf16x8*>(&Ws[(ct * 16 + m16) * 72 + quad * 8 + kk]);
        acc[ct] = __builtin_amdgcn_mfma_f32_16x16x32_bf16(a, b, acc[ct], 0, 0, 0);
      }
    }
  }

  float bn[4];
#pragma unroll
  for (int ct = 0; ct < 4; ct++) bn[ct] = bias[n0 + ct * 16 + m16];
#pragma unroll
  for (int ct = 0; ct < 4; ct++) {
    int n = n0 + ct * 16 + m16;
#pragma unroll
    for (int r = 0; r < 4; r++) {
      int m = m0 + wv * 16 + quad * 4 + r;
      Cout[(size_t)m * DM + n] = acc[ct][r] + bn[ct];
    }
  }
}

// ---------------------------------------------------------------------------
// Flash attention (VERBATIM round-8 known-good): MFMA, fixed-shift softmax,
// split-K x2 within the block, S^T scheme with octal key permutation.
__global__ __launch_bounds__(512) void attn_mfma(
    const u16* __restrict__ Q, const u16* __restrict__ K,
    const u16* __restrict__ Vt2, const u64* __restrict__ mbits,
    u16* __restrict__ O) {
  __shared__ u16 SM[2][3][64 * 72];   // [group][{Ks,Vs,Ps}] 55.3 KB
  __shared__ float Lm[64];

  const int t = threadIdx.x;
  const int lane = t & 63, wv = t >> 6;
  const int m16 = lane & 15, quad = lane >> 4;
  const int g  = wv >> 2;    // key-half group
  const int w4 = wv & 3;     // wave within group (16 q-rows)
  const int tt = t & 255;
  const int q0 = blockIdx.x * 64;
  const int h = blockIdx.y;
  const size_t hoff = (size_t)h * S_LEN * DK;
  const size_t kbase = hoff + (size_t)g * 2048 * DK;
  const u16* V2h = Vt2 + (size_t)h * DK * S_LEN;   // rows d, cols c*512+m'

  u16* Ks = SM[g][0];
  u16* Vs = SM[g][1];
  u16* Ps = SM[g][2];

  // Q fragments straight from global (pre-scaled by 0.125*log2e in Q-GEMM)
  const u16* qptr = Q + hoff + (size_t)(q0 + w4 * 16 + m16) * DK + quad * 8;
  bf16x8 qlo = *reinterpret_cast<const bf16x8*>(qptr);
  bf16x8 qhi = *reinterpret_cast<const bf16x8*>(qptr + 32);

  // ones B-fragment (row-sum of P via MFMA)
  union { u16 u[8]; bf16x8 v; } onesu;
#pragma unroll
  for (int j = 0; j < 8; j++) onesu.u[j] = 0x3F80;
  const bf16x8 ones = onesu.v;

  f32x4 acc_o[4];
  f32x4 acc_l = (f32x4)0.f;
#pragma unroll
  for (int dt = 0; dt < 4; dt++) acc_o[dt] = (f32x4)0.f;

  const int mshift = 32 * (quad & 1) + (quad >> 1);
  const int prow = (w4 * 16 + m16) * 72;

  for (int k0 = 0; k0 < 2048; k0 += 64) {
    const int kg = g * 2048 + k0;   // global key tile base
    // stage K rows permuted; stage V from Vt2 (lands permuted automatically)
#pragma unroll
    for (int c0 = 0; c0 < 2; c0++) {
      int c = tt + c0 * 256;
      int rg = c >> 3, cc = c & 7;
      int rperm = ((rg & 7) << 3) | (rg >> 3);
      *reinterpret_cast<uint4*>(&Ks[rperm * 72 + cc * 8]) =
          *reinterpret_cast<const uint4*>(&K[kbase + (size_t)(k0 + rg) * DK + cc * 8]);
      *reinterpret_cast<uint4*>(&Vs[rg * 72 + cc * 8]) =
          *reinterpret_cast<const uint4*>(&V2h[(size_t)rg * S_LEN + cc * 512 + (kg >> 3)]);
    }
    // one mask word per lane: query q0+w4*16+m16, keys [kg, kg+64)
    u64 mq = mbits[(size_t)(q0 + w4 * 16 + m16) * 64 + (kg >> 6)];
    u32 mm = (u32)(mq >> mshift);
    __syncthreads();   // tiles ready

    // S^T = K @ Q^T (log2-domain): lane reg (ct,r) = ktil 16ct+quad*4+r, q=m16
    f32x4 s[4];
#pragma unroll
    for (int ct = 0; ct < 4; ct++) s[ct] = (f32x4)0.f;
#pragma unroll
    for (int ct = 0; ct < 4; ct++) {
      bf16x8 klo = *reinterpret_cast<const bf16x8*>(&Ks[(ct * 16 + m16) * 72 + quad * 8]);
      bf16x8 khi = *reinterpret_cast<const bf16x8*>(&Ks[(ct * 16 + m16) * 72 + quad * 8 + 32]);
      s[ct] = __builtin_amdgcn_mfma_f32_16x16x32_bf16(klo, qlo, s[ct], 0, 0, 0);
      s[ct] = __builtin_amdgcn_mfma_f32_16x16x32_bf16(khi, qhi, s[ct], 0, 0, 0);
    }

    // p = exp2(s - FMAX), masked -> 0; true key bit = 8r + 2ct (after mshift)
#pragma unroll
    for (int ct = 0; ct < 4; ct++) {
      float p0 = __builtin_amdgcn_exp2f(((mm >> (2 * ct)) & 1u)      ? -1e9f : s[ct][0] - FMAX);
      float p1 = __builtin_amdgcn_exp2f(((mm >> (8 + 2 * ct)) & 1u)  ? -1e9f : s[ct][1] - FMAX);
      float p2 = __builtin_amdgcn_exp2f(((mm >> (16 + 2 * ct)) & 1u) ? -1e9f : s[ct][2] - FMAX);
      float p3 = __builtin_amdgcn_exp2f(((mm >> (24 + 2 * ct)) & 1u) ? -1e9f : s[ct][3] - FMAX);
      u32 pk01 = (u32)f2bf(p0) | ((u32)f2bf(p1) << 16);
      u32 pk23 = (u32)f2bf(p2) | ((u32)f2bf(p3) << 16);
      *reinterpret_cast<uint2*>(&Ps[prow + ct * 16 + quad * 4]) = make_uint2(pk01, pk23);
    }
    // Ps rows are wave-private: no barrier needed.

    // O += P @ V ; l += P @ 1   (all in permuted key space)
    bf16x8 plo = *reinterpret_cast<const bf16x8*>(&Ps[prow + quad * 8]);
    bf16x8 phi = *reinterpret_cast<const bf16x8*>(&Ps[prow + quad * 8 + 32]);
#pragma unroll
    for (int dt = 0; dt < 4; dt++) {
      bf16x8 vlo = *reinterpret_cast<const bf16x8*>(&Vs[(dt * 16 + m16) * 72 + quad * 8]);
      bf16x8 vhi = *reinterpret_cast<const bf16x8*>(&Vs[(dt * 16 + m16) * 72 + quad * 8 + 32]);
      acc_o[dt] = __builtin_amdgcn_mfma_f32_16x16x32_bf16(plo, vlo, acc_o[dt], 0, 0, 0);
      acc_o[dt] = __builtin_amdgcn_mfma_f32_16x16x32_bf16(phi, vhi, acc_o[dt], 0, 0, 0);
    }
    acc_l = __builtin_amdgcn_mfma_f32_16x16x32_bf16(plo, ones, acc_l, 0, 0, 0);
    acc_l = __builtin_amdgcn_mfma_f32_16x16x32_bf16(phi, ones, acc_l, 0, 0, 0);
    __syncthreads();   // all reads done before next staging
  }

  // merge the two key-halves (pure sums, fixed shift) through LDS
  float* Om = reinterpret_cast<float*>(&SM[1][0][0]);   // 16 KB in group-1 Ks+Vs
  if (g == 1) {
#pragma unroll
    for (int dt = 0; dt < 4; dt++)
#pragma unroll
      for (int r = 0; r < 4; r++)
        Om[(w4 * 16 + quad * 4 + r) * 64 + dt * 16 + m16] = acc_o[dt][r];
    if (m16 == 0) {
#pragma unroll
      for (int r = 0; r < 4; r++) Lm[w4 * 16 + quad * 4 + r] = acc_l[r];
    }
  }
  __syncthreads();
  if (g == 0) {
    float rl[4];
#pragma unroll
    for (int r = 0; r < 4; r++)
      rl[r] = 1.f / (acc_l[r] + Lm[w4 * 16 + quad * 4 + r]);
#pragma unroll
    for (int dt = 0; dt < 4; dt++)
#pragma unroll
      for (int r = 0; r < 4; r++) {
        float o = acc_o[dt][r] + Om[(w4 * 16 + quad * 4 + r) * 64 + dt * 16 + m16];
        O[(size_t)(q0 + w4 * 16 + quad * 4 + r) * DM + h * DK + dt * 16 + m16] =
            f2bf(o * rl[r]);
      }
  }
}

// ---------------------------------------------------------------------------
extern "C" void kernel_launch(void* const* d_in, const int* in_sizes, int n_in,
                              void* d_out, int out_size, void* d_ws, size_t ws_size,
                              hipStream_t stream) {
  const float* x    = (const float*)d_in[0];
  const int*   mask = (const int*)d_in[1];
  const float* wq_w = (const float*)d_in[2];
  const float* wq_b = (const float*)d_in[3];
  const float* wk_w = (const float*)d_in[4];
  const float* wk_b = (const float*)d_in[5];
  const float* wv_w = (const float*)d_in[6];
  const float* wv_b = (const float*)d_in[7];
  const float* dw   = (const float*)d_in[8];
  const float* db   = (const float*)d_in[9];

  // ws (u16 elems): xb 2M | wcat 768K | dwb 256K | Qb/Kb/Vt2/Ob 2M each | mb 256K u64
  u16* xb   = (u16*)d_ws;
  u16* wcat = xb   + 2097152;
  u16* dwb  = wcat + 786432;
  u16* Qb   = dwb  + 262144;
  u16* Kb   = Qb   + 2097152;
  u16* Vt2  = Kb   + 2097152;
  u16* Ob   = Vt2  + 2097152;
  u64* mb   = (u64*)(Ob + 2097152);

  pack_mask<<<(S_LEN * S_LEN) / 256, 256, 0, stream>>>(mask, mb);
  convert_all<<<3072, 256, 0, stream>>>(x, wq_w, wk_w, wv_w, dw, xb, wcat, dwb);

  qkv_gemm<<<dim3(12, 64), 256, 0, stream>>>(xb, wcat, wq_b, wk_b, wv_b,
                                             Qb, Kb, Vt2);

  attn_mfma<<<dim3(S_LEN / 64, NH), 512, 0, stream>>>(Qb, Kb, Vt2, mb, Ob);

  dense_gemm<<<dim3(8, 64), 256, 0, stream>>>(Ob, dwb, db, (float*)d_out);
}

// Round 12
// 225.377 us; speedup vs baseline: 1.1471x; 1.0635x over previous
//
#include <hip/hip_runtime.h>
#include <hip/hip_bf16.h>

#define S_LEN 4096
#define DM    512
#define NH    8
#define DK    64

typedef __attribute__((ext_vector_type(8))) __bf16 bf16x8;
typedef __attribute__((ext_vector_type(4))) float  f32x4;
typedef unsigned short u16;
typedef unsigned int   u32;
typedef unsigned long long u64;

// Q-GEMM epilogue scale: 1/sqrt(64) * log2(e)  (softmax in log2 domain)
#define SQ_SCALE (0.125f * 1.44269504f)
// Fixed softmax shift (log2-domain). Shift-invariant; l-division restores scale.
#define FMAX 12.0f

__device__ __forceinline__ u16 f2bf(float f) {
  union { float f; u32 i; } v; v.f = f;
  u32 r = v.i + 0x7fff + ((v.i >> 16) & 1);   // RNE
  return (u16)(r >> 16);
}
__device__ __forceinline__ float bf2f(u16 u) {
  union { u32 i; float f; } v; v.i = ((u32)u) << 16; return v.f;
}

// ---------------------------------------------------------------------------
// Pack mask [4096,4096] int32 (0/1) -> u64[4096][64]; bit=1 means masked.
__global__ __launch_bounds__(256) void pack_mask(const int* __restrict__ mask,
                                                 u64* __restrict__ out) {
  int gid = blockIdx.x * 256 + threadIdx.x;
  u64 b = __ballot(mask[gid] != 0);
  if ((threadIdx.x & 63) == 0) out[gid >> 6] = b;
}

// ---------------------------------------------------------------------------
// fp32 -> bf16 conversion; wq/wk/wv land contiguously (one [1536][512] matrix).
__global__ __launch_bounds__(256) void convert_all(
    const float* __restrict__ x, const float* __restrict__ wq,
    const float* __restrict__ wk, const float* __restrict__ wv,
    const float* __restrict__ dw,
    u16* __restrict__ xb, u16* __restrict__ wcat, u16* __restrict__ dwb) {
  int b = blockIdx.x;
  const float* src; u16* dst; size_t off;
  if      (b < 2048) { src = x;  dst = xb;   off = (size_t)b * 1024; }
  else if (b < 2304) { src = wq; dst = wcat; off = (size_t)(b - 2048) * 1024; }
  else if (b < 2560) { src = wk; dst = wcat + 262144; off = (size_t)(b - 2304) * 1024; }
  else if (b < 2816) { src = wv; dst = wcat + 524288; off = (size_t)(b - 2560) * 1024; }
  else               { src = dw; dst = dwb;  off = (size_t)(b - 2816) * 1024; }
  size_t i = off + (size_t)threadIdx.x * 4;
  float4 v = *reinterpret_cast<const float4*>(src + i);
  ushort4 o = make_ushort4(f2bf(v.x), f2bf(v.y), f2bf(v.z), f2bf(v.w));
  *reinterpret_cast<ushort4*>(dst + i) = o;
}

// ---------------------------------------------------------------------------
// Fused QKV projection, 64(m) x 128(n) tiles: C[4096,1536] = x @ Wcat^T + bias.
// grid (12, 64). seg 0=Q (scaled), 1=K, 2=V.
// V output layout V4[(h*64+d)][tile*64 + slot] where for true key kappa =
// m'*8+c (from _split_heads: h=m>>9, d=n&63, key=(m&511)*8+(n>>6)):
// tile = m'>>3, slot = (c&1)*32 + (c>>1)*8 + (m'&7).  This slot order makes
// attn's P C-layout directly usable as the PV A-fragment (see attn_mfma).
__global__ __launch_bounds__(256) void qkv_gemm(
    const u16* __restrict__ A, const u16* __restrict__ Wcat,
    const float* __restrict__ bq, const float* __restrict__ bk,
    const float* __restrict__ bv,
    u16* __restrict__ Qb, u16* __restrict__ Kb, u16* __restrict__ V4) {
  __shared__ u16 As[64 * 72];    // 9.2 KB
  __shared__ u16 Ws[128 * 72];   // 18.4 KB (reused as T in V epilogue)
  const int t = threadIdx.x;
  const int lane = t & 63, wv = t >> 6;
  const int m16 = lane & 15, quad = lane >> 4;
  const int n0g = blockIdx.x * 128, m0 = blockIdx.y * 64;
  const int seg = n0g >> 9;
  const int n0 = n0g & 511;
  const int mq = wv >> 1, nq = wv & 1;   // wave quadrant

  f32x4 acc[2][4];
#pragma unroll
  for (int i = 0; i < 2; i++)
#pragma unroll
    for (int j = 0; j < 4; j++) acc[i][j] = (f32x4)0.f;

  for (int k0 = 0; k0 < DM; k0 += 64) {
    __syncthreads();
#pragma unroll
    for (int c0 = 0; c0 < 2; c0++) {       // A: 64x64 = 512 uint4
      int c = t + c0 * 256;
      int row = c >> 3, col = (c & 7) * 8;
      *reinterpret_cast<uint4*>(&As[row * 72 + col]) =
          *reinterpret_cast<const uint4*>(&A[(size_t)(m0 + row) * DM + k0 + col]);
    }
#pragma unroll
    for (int c0 = 0; c0 < 4; c0++) {       // W: 128x64 = 1024 uint4
      int c = t + c0 * 256;
      int row = c >> 3, col = (c & 7) * 8;
      *reinterpret_cast<uint4*>(&Ws[row * 72 + col]) =
          *reinterpret_cast<const uint4*>(&Wcat[(size_t)(n0g + row) * DM + k0 + col]);
    }
    __syncthreads();
#pragma unroll
    for (int kk = 0; kk < 64; kk += 32) {
      bf16x8 a0 = *reinterpret_cast<const bf16x8*>(&As[(mq * 32 + m16) * 72 + quad * 8 + kk]);
      bf16x8 a1 = *reinterpret_cast<const bf16x8*>(&As[(mq * 32 + 16 + m16) * 72 + quad * 8 + kk]);
#pragma unroll
      for (int ct = 0; ct < 4; ct++) {
        bf16x8 b = *reinterpret_cast<const bf16x8*>(&Ws[(nq * 64 + ct * 16 + m16) * 72 + quad * 8 + kk]);
        acc[0][ct] = __builtin_amdgcn_mfma_f32_16x16x32_bf16(a0, b, acc[0][ct], 0, 0, 0);
        acc[1][ct] = __builtin_amdgcn_mfma_f32_16x16x32_bf16(a1, b, acc[1][ct], 0, 0, 0);
      }
    }
  }

  const float* bias = (seg == 0) ? bq : (seg == 1) ? bk : bv;
  const float scale = (seg == 0) ? SQ_SCALE : 1.f;
  float bn[4];
#pragma unroll
  for (int ct = 0; ct < 4; ct++) bn[ct] = bias[n0 + nq * 64 + ct * 16 + m16];

  if (seg == 2) {
    // transpose through LDS (reuse Ws as T[128 nl][64 ml], stride 72)
    __syncthreads();   // all fragment reads of Ws done
    u16* T = Ws;
#pragma unroll
    for (int rt = 0; rt < 2; rt++)
#pragma unroll
      for (int ct = 0; ct < 4; ct++)
#pragma unroll
        for (int r = 0; r < 4; r++)
          T[(nq * 64 + ct * 16 + m16) * 72 + mq * 32 + rt * 16 + quad * 4 + r] =
              f2bf(acc[rt][ct][r] + bn[ct]);
    __syncthreads();
    const int h    = m0 >> 9;
    const int mp   = m0 & 511;   // multiple of 64
    const int cseg = n0 >> 7;    // 0..3
#pragma unroll
    for (int c0 = 0; c0 < 4; c0++) {       // 1024 uint4 copies
      int c = t + c0 * 256;
      int d  = c >> 4;          // 0..63
      int tl = (c >> 1) & 7;    // 0..7
      int cl = c & 1;           // 0..1
      uint4 v = *reinterpret_cast<const uint4*>(&T[(cl * 64 + d) * 72 + tl * 8]);
      *reinterpret_cast<uint4*>(
          &V4[(size_t)(h * 64 + d) * 4096 + ((mp >> 3) + tl) * 64 + cl * 32 + cseg * 8]) = v;
    }
  } else {
    u16* dst = (seg == 0) ? Qb : Kb;
#pragma unroll
    for (int rt = 0; rt < 2; rt++)
#pragma unroll
      for (int ct = 0; ct < 4; ct++) {
        int n = n0 + nq * 64 + ct * 16 + m16;
#pragma unroll
        for (int r = 0; r < 4; r++) {
          int m = m0 + mq * 32 + rt * 16 + quad * 4 + r;
          dst[(size_t)m * DM + n] = f2bf((acc[rt][ct][r] + bn[ct]) * scale);
        }
      }
  }
}

// ---------------------------------------------------------------------------
// Dense out-proj, 64x64 tiles: C[4096,512](f32) = A @ dw^T + db. grid (8,64).
__global__ __launch_bounds__(256) void dense_gemm(
    const u16* __restrict__ A, const u16* __restrict__ W,
    const float* __restrict__ bias, float* __restrict__ Cout) {
  __shared__ u16 As[64 * 72];
  __shared__ u16 Ws[64 * 72];
  const int t = threadIdx.x;
  const int lane = t & 63, wv = t >> 6;
  const int m16 = lane & 15, quad = lane >> 4;
  const int n0 = blockIdx.x * 64, m0 = blockIdx.y * 64;

  f32x4 acc[4];
#pragma unroll
  for (int j = 0; j < 4; j++) acc[j] = (f32x4)0.f;

  for (int k0 = 0; k0 < DM; k0 += 64) {
    __syncthreads();
#pragma unroll
    for (int c0 = 0; c0 < 2; c0++) {
      int c = t + c0 * 256;
      int row = c >> 3, col = (c & 7) * 8;
      *reinterpret_cast<uint4*>(&As[row * 72 + col]) =
          *reinterpret_cast<const uint4*>(&A[(size_t)(m0 + row) * DM + k0 + col]);
      *reinterpret_cast<uint4*>(&Ws[row * 72 + col]) =
          *reinterpret_cast<const uint4*>(&W[(size_t)(n0 + row) * DM + k0 + col]);
    }
    __syncthreads();
#pragma unroll
    for (int kk = 0; kk < 64; kk += 32) {
      bf16x8 a = *reinterpret_cast<const bf16x8*>(&As[(wv * 16 + m16) * 72 + quad * 8 + kk]);
#pragma unroll
      for (int ct = 0; ct < 4; ct++) {
        bf16x8 b = *reinterpret_cast<const bf16x8*>(&Ws[(ct * 16 + m16) * 72 + quad * 8 + kk]);
        acc[ct] = __builtin_amdgcn_mfma_f32_16x16x32_bf16(a, b, acc[ct], 0, 0, 0);
      }
    }
  }

  float bn[4];
#pragma unroll
  for (int ct = 0; ct < 4; ct++) bn[ct] = bias[n0 + ct * 16 + m16];
#pragma unroll
  for (int ct = 0; ct < 4; ct++) {
    int n = n0 + ct * 16 + m16;
#pragma unroll
    for (int r = 0; r < 4; r++) {
      int m = m0 + wv * 16 + quad * 4 + r;
      Cout[(size_t)m * DM + n] = acc[ct][r] + bn[ct];
    }
  }
}

// ---------------------------------------------------------------------------
// exp2 + mask + pack one q-subtile's scores into the two PV A-fragments.
// Mask bit for C slot (ct,r): true key = 32(ct&1) + 16(r>>1) + 8(r&1)
// + 2*quad + (ct>>1); lo/hi are the lane's mask word pre-shifted by 2*quad.
__device__ __forceinline__ void pack_p(const f32x4* s, u32 lo, u32 hi,
                                       uint4& o0, uint4& o1) {
  u32 pk[8];
#pragma unroll
  for (int ct = 0; ct < 4; ct++) {
    u32 w = (ct & 1) ? hi : lo;
    int b = ct >> 1;
    float p0 = __builtin_amdgcn_exp2f(((w >> b) & 1u)        ? -1e9f : s[ct][0]);
    float p1 = __builtin_amdgcn_exp2f(((w >> (b + 8)) & 1u)  ? -1e9f : s[ct][1]);
    float p2 = __builtin_amdgcn_exp2f(((w >> (b + 16)) & 1u) ? -1e9f : s[ct][2]);
    float p3 = __builtin_amdgcn_exp2f(((w >> (b + 24)) & 1u) ? -1e9f : s[ct][3]);
    pk[2 * ct]     = __builtin_amdgcn_perm(__float_as_uint(p1) + 0x8000u,
                                           __float_as_uint(p0) + 0x8000u, 0x07060302u);
    pk[2 * ct + 1] = __builtin_amdgcn_perm(__float_as_uint(p3) + 0x8000u,
                                           __float_as_uint(p2) + 0x8000u, 0x07060302u);
  }
  o0 = make_uint4(pk[0], pk[1], pk[2], pk[3]);
  o1 = make_uint4(pk[4], pk[5], pk[6], pk[7]);
}

// ---------------------------------------------------------------------------
// Flash attention v3: fixed-shift softmax, grid split-K x4, NO P roundtrip.
// Key axis co-permuted in K staging (sigma bit-shuffle) and V4 layout so the
// S^T C-layout registers, exp2'd and bf16-packed, ARE the PV A-fragments.
// Each wave owns 32 q (2 subtiles) -> every K/V fragment read feeds 2 MFMAs.
// Block 256 thr = 4 waves = 128 q; grid (32, 8, 4); partials merged after.
__global__ __launch_bounds__(256, 4) void attn_mfma(
    const u16* __restrict__ Q, const u16* __restrict__ K,
    const u16* __restrict__ V4, const u64* __restrict__ mbits,
    u16* __restrict__ Op, float* __restrict__ Lp) {
  __shared__ u16 Ks[64 * 72];
  __shared__ u16 Vs[64 * 72];

  const int t = threadIdx.x;
  const int lane = t & 63, w4 = t >> 6;
  const int m16 = lane & 15, quad = lane >> 4;
  const int q0 = blockIdx.x * 128;
  const int h = blockIdx.y;
  const int g = blockIdx.z;          // key quarter: 1024 keys, 16 tiles
  const size_t hoff = (size_t)h * S_LEN * DK;
  const size_t kbase = hoff + (size_t)g * 1024 * DK;

  // Q fragments for the wave's two q-subtiles (pre-scaled in Q-GEMM)
  const u16* qpA = Q + hoff + (size_t)(q0 + w4 * 32 + m16) * DK + quad * 8;
  bf16x8 qloA = *reinterpret_cast<const bf16x8*>(qpA);
  bf16x8 qhiA = *reinterpret_cast<const bf16x8*>(qpA + 32);
  bf16x8 qloB = *reinterpret_cast<const bf16x8*>(qpA + 16 * DK);
  bf16x8 qhiB = *reinterpret_cast<const bf16x8*>(qpA + 16 * DK + 32);

  union { u16 u[8]; bf16x8 v; } onesu;
#pragma unroll
  for (int j = 0; j < 8; j++) onesu.u[j] = 0x3F80;
  const bf16x8 ones = onesu.v;

  f32x4 accA[4], accB[4];
  f32x4 acc_lA = (f32x4)0.f, acc_lB = (f32x4)0.f;
#pragma unroll
  for (int dt = 0; dt < 4; dt++) { accA[dt] = (f32x4)0.f; accB[dt] = (f32x4)0.f; }

  for (int k0 = 0; k0 < 1024; k0 += 64) {
    const int kg = g * 1024 + k0;
    // stage K rows at sigma(rg) = [k0,k5,k2,k1,k4,k3]; V4 already slot-ordered
#pragma unroll
    for (int c0 = 0; c0 < 2; c0++) {
      int c = t + c0 * 256;
      int rg = c >> 3, cc = c & 7;
      int sr = ((rg & 1) << 5) | (((rg >> 5) & 1) << 4) | (((rg >> 2) & 1) << 3) |
               (((rg >> 1) & 1) << 2) | (((rg >> 4) & 1) << 1) | ((rg >> 3) & 1);
      *reinterpret_cast<uint4*>(&Ks[sr * 72 + cc * 8]) =
          *reinterpret_cast<const uint4*>(&K[kbase + (size_t)(k0 + rg) * DK + cc * 8]);
      *reinterpret_cast<uint4*>(&Vs[rg * 72 + cc * 8]) =
          *reinterpret_cast<const uint4*>(&V4[(size_t)(h * 64 + rg) * 4096 + kg + cc * 8]);
    }
    u64 mqA = mbits[(size_t)(q0 + w4 * 32 + m16) * 64 + (kg >> 6)] >> (2 * quad);
    u64 mqB = mbits[(size_t)(q0 + w4 * 32 + 16 + m16) * 64 + (kg >> 6)] >> (2 * quad);
    __syncthreads();   // tiles ready

    // S^T - FMAX for both q-subtiles; each K fragment feeds 2 MFMAs
    f32x4 sA[4], sB[4];
#pragma unroll
    for (int ct = 0; ct < 4; ct++) { sA[ct] = (f32x4)(-FMAX); sB[ct] = (f32x4)(-FMAX); }
#pragma unroll
    for (int ct = 0; ct < 4; ct++) {
      bf16x8 klo = *reinterpret_cast<const bf16x8*>(&Ks[(ct * 16 + m16) * 72 + quad * 8]);
      bf16x8 khi = *reinterpret_cast<const bf16x8*>(&Ks[(ct * 16 + m16) * 72 + quad * 8 + 32]);
      sA[ct] = __builtin_amdgcn_mfma_f32_16x16x32_bf16(klo, qloA, sA[ct], 0, 0, 0);
      sA[ct] = __builtin_amdgcn_mfma_f32_16x16x32_bf16(khi, qhiA, sA[ct], 0, 0, 0);
      sB[ct] = __builtin_amdgcn_mfma_f32_16x16x32_bf16(klo, qloB, sB[ct], 0, 0, 0);
      sB[ct] = __builtin_amdgcn_mfma_f32_16x16x32_bf16(khi, qhiB, sB[ct], 0, 0, 0);
    }

    // exp2 + pack: registers become the PV A-fragments directly (no LDS)
    union { uint4 i; bf16x8 v; } pA0, pA1, pB0, pB1;
    pack_p(sA, (u32)mqA, (u32)(mqA >> 32), pA0.i, pA1.i);
    pack_p(sB, (u32)mqB, (u32)(mqB >> 32), pB0.i, pB1.i);

    // O += P @ V ; l += P @ 1; each V fragment feeds 2 MFMAs
#pragma unroll
    for (int dt = 0; dt < 4; dt++) {
      bf16x8 vlo = *reinterpret_cast<const bf16x8*>(&Vs[(dt * 16 + m16) * 72 + quad * 8]);
      bf16x8 vhi = *reinterpret_cast<const bf16x8*>(&Vs[(dt * 16 + m16) * 72 + quad * 8 + 32]);
      accA[dt] = __builtin_amdgcn_mfma_f32_16x16x32_bf16(pA0.v, vlo, accA[dt], 0, 0, 0);
      accA[dt] = __builtin_amdgcn_mfma_f32_16x16x32_bf16(pA1.v, vhi, accA[dt], 0, 0, 0);
      accB[dt] = __builtin_amdgcn_mfma_f32_16x16x32_bf16(pB0.v, vlo, accB[dt], 0, 0, 0);
      accB[dt] = __builtin_amdgcn_mfma_f32_16x16x32_bf16(pB1.v, vhi, accB[dt], 0, 0, 0);
    }
    acc_lA = __builtin_amdgcn_mfma_f32_16x16x32_bf16(pA0.v, ones, acc_lA, 0, 0, 0);
    acc_lA = __builtin_amdgcn_mfma_f32_16x16x32_bf16(pA1.v, ones, acc_lA, 0, 0, 0);
    acc_lB = __builtin_amdgcn_mfma_f32_16x16x32_bf16(pB0.v, ones, acc_lB, 0, 0, 0);
    acc_lB = __builtin_amdgcn_mfma_f32_16x16x32_bf16(pB1.v, ones, acc_lB, 0, 0, 0);
    __syncthreads();   // all tile reads done before next staging
  }

  // partial O (unnormalized bf16) + partial l (f32)
  u16* Og = Op + (size_t)g * 2097152;
#pragma unroll
  for (int dt = 0; dt < 4; dt++)
#pragma unroll
    for (int r = 0; r < 4; r++) {
      Og[(size_t)(q0 + w4 * 32 + quad * 4 + r) * DM + h * DK + dt * 16 + m16] =
          f2bf(accA[dt][r]);
      Og[(size_t)(q0 + w4 * 32 + 16 + quad * 4 + r) * DM + h * DK + dt * 16 + m16] =
          f2bf(accB[dt][r]);
    }
  if (m16 == 0) {
#pragma unroll
    for (int r = 0; r < 4; r++) {
      Lp[g * 32768 + h * 4096 + q0 + w4 * 32 + quad * 4 + r] = acc_lA[r];
      Lp[g * 32768 + h * 4096 + q0 + w4 * 32 + 16 + quad * 4 + r] = acc_lB[r];
    }
  }
}

// ---------------------------------------------------------------------------
// Merge the four key-quarter partials: Out = sum(O_g) / sum(l_g). bf16 out.
__global__ __launch_bounds__(256) void attn_merge(
    const u16* __restrict__ Op, const float* __restrict__ Lp,
    u16* __restrict__ Out) {
  int i8 = (blockIdx.x * 256 + threadIdx.x) * 8;   // 8 elems/thread, same (q,h)
  int q = i8 >> 9;
  int h = (i8 >> 6) & 7;
  float l = 0.f;
#pragma unroll
  for (int part = 0; part < 4; part++) l += Lp[part * 32768 + h * 4096 + q];
  float rl = 1.f / l;
  float o[8];
#pragma unroll
  for (int j = 0; j < 8; j++) o[j] = 0.f;
#pragma unroll
  for (int part = 0; part < 4; part++) {
    ushort4 v0 = *reinterpret_cast<const ushort4*>(Op + part * 2097152 + i8);
    ushort4 v1 = *reinterpret_cast<const ushort4*>(Op + part * 2097152 + i8 + 4);
    o[0] += bf2f(v0.x); o[1] += bf2f(v0.y); o[2] += bf2f(v0.z); o[3] += bf2f(v0.w);
    o[4] += bf2f(v1.x); o[5] += bf2f(v1.y); o[6] += bf2f(v1.z); o[7] += bf2f(v1.w);
  }
  ushort4 o0 = make_ushort4(f2bf(o[0] * rl), f2bf(o[1] * rl),
                            f2bf(o[2] * rl), f2bf(o[3] * rl));
  ushort4 o1 = make_ushort4(f2bf(o[4] * rl), f2bf(o[5] * rl),
                            f2bf(o[6] * rl), f2bf(o[7] * rl));
  *reinterpret_cast<ushort4*>(Out + i8) = o0;
  *reinterpret_cast<ushort4*>(Out + i8 + 4) = o1;
}

// ---------------------------------------------------------------------------
extern "C" void kernel_launch(void* const* d_in, const int* in_sizes, int n_in,
                              void* d_out, int out_size, void* d_ws, size_t ws_size,
                              hipStream_t stream) {
  const float* x    = (const float*)d_in[0];
  const int*   mask = (const int*)d_in[1];
  const float* wq_w = (const float*)d_in[2];
  const float* wq_b = (const float*)d_in[3];
  const float* wk_w = (const float*)d_in[4];
  const float* wk_b = (const float*)d_in[5];
  const float* wv_w = (const float*)d_in[6];
  const float* wv_b = (const float*)d_in[7];
  const float* dw   = (const float*)d_in[8];
  const float* db   = (const float*)d_in[9];

  // ws (u16 elems): xb 2M | wcat 768K | dwb 256K | Qb/Kb/V4 2M each |
  // Opart 4x2M | mb 256K u64 | Lp 128K f32.  ~37 MB total.
  u16* xb    = (u16*)d_ws;
  u16* wcat  = xb    + 2097152;
  u16* dwb   = wcat  + 786432;
  u16* Qb    = dwb   + 262144;
  u16* Kb    = Qb    + 2097152;
  u16* V4    = Kb    + 2097152;
  u16* Opart = V4    + 2097152;
  u64* mb    = (u64*)(Opart + 4 * 2097152);
  float* Lp  = (float*)(mb + 262144);

  pack_mask<<<(S_LEN * S_LEN) / 256, 256, 0, stream>>>(mask, mb);
  convert_all<<<3072, 256, 0, stream>>>(x, wq_w, wk_w, wv_w, dw, xb, wcat, dwb);

  qkv_gemm<<<dim3(12, 64), 256, 0, stream>>>(xb, wcat, wq_b, wk_b, wv_b,
                                             Qb, Kb, V4);

  attn_mfma<<<dim3(32, NH, 4), 256, 0, stream>>>(Qb, Kb, V4, mb, Opart, Lp);
  attn_merge<<<1024, 256, 0, stream>>>(Opart, Lp, Qb);

  dense_gemm<<<dim3(8, 64), 256, 0, stream>>>(Qb, dwb, db, (float*)d_out);
}